// Round 1
// baseline (669.166 us; speedup 1.0000x reference)
//
#include <hip/hip_runtime.h>

#define N_SAMPLES 131072
#define N_CLASSES 1000
#define BINS 10

// d_ws layout:
//   [0, N_SAMPLES) floats            : values[i] = -log_softmax(pred_i)[t_i]
//   at N_SAMPLES (as uint*) slot 0   : vmax bits (atomicMax on uint; values>=0)
//   slots 1..10                      : counts[10] (uint)
//   slots 11..20                     : sums[10] (float)

__global__ __launch_bounds__(256) void values_kernel(const float* __restrict__ pred,
                                                     const int* __restrict__ target,
                                                     float* __restrict__ values) {
    const int wave = threadIdx.x >> 6;   // 4 waves per block, 1 row per wave
    const int lane = threadIdx.x & 63;
    const int row = blockIdx.x * 4 + wave;
    if (row >= N_SAMPLES) return;

    const float4* __restrict__ rp = (const float4*)(pred + (size_t)row * N_CLASSES);

    // All four 16B loads issue unconditionally (no exec-mask branch between them).
    // Row has exactly 250 float4; k=0..2 always in-range, k=3 tail clamps the
    // address and masks the values with -INF (exp(-INF - m) == 0, fmax no-op).
    float4 r0 = rp[lane];
    float4 r1 = rp[64 + lane];
    float4 r2 = rp[128 + lane];
    const int i3 = (192 + lane < 250) ? (192 + lane) : 249;
    float4 r3 = rp[i3];

    // Target logit: wave-uniform address -> single broadcast transaction,
    // latency hidden under the row loads above.
    const int t = target[row];
    const float xt = pred[(size_t)row * N_CLASSES + t];

    const bool v3 = (192 + lane) < 250;
    const float NEG_INF = -INFINITY;
    float r3x = v3 ? r3.x : NEG_INF;
    float r3y = v3 ? r3.y : NEG_INF;
    float r3z = v3 ? r3.z : NEG_INF;
    float r3w = v3 ? r3.w : NEG_INF;

    // 4 independent partial maxes -> tree combine (breaks the serial fmax chain)
    float m0 = fmaxf(fmaxf(r0.x, r0.y), fmaxf(r0.z, r0.w));
    float m1 = fmaxf(fmaxf(r1.x, r1.y), fmaxf(r1.z, r1.w));
    float m2 = fmaxf(fmaxf(r2.x, r2.y), fmaxf(r2.z, r2.w));
    float m3 = fmaxf(fmaxf(r3x, r3y), fmaxf(r3z, r3w));
    float lmax = fmaxf(fmaxf(m0, m1), fmaxf(m2, m3));
#pragma unroll
    for (int off = 32; off > 0; off >>= 1)
        lmax = fmaxf(lmax, __shfl_xor(lmax, off, 64));

    // 4 independent partial sums (ILP on the add chain); masked lanes contribute
    // exp(-INF - lmax) == 0 exactly.
    float s0 = __expf(r0.x - lmax) + __expf(r0.y - lmax) +
               __expf(r0.z - lmax) + __expf(r0.w - lmax);
    float s1 = __expf(r1.x - lmax) + __expf(r1.y - lmax) +
               __expf(r1.z - lmax) + __expf(r1.w - lmax);
    float s2 = __expf(r2.x - lmax) + __expf(r2.y - lmax) +
               __expf(r2.z - lmax) + __expf(r2.w - lmax);
    float s3 = __expf(r3x - lmax) + __expf(r3y - lmax) +
               __expf(r3z - lmax) + __expf(r3w - lmax);
    float s = (s0 + s1) + (s2 + s3);
#pragma unroll
    for (int off = 32; off > 0; off >>= 1)
        s += __shfl_xor(s, off, 64);

    if (lane == 0)
        values[row] = logf(s) + lmax - xt;   // logsumexp - x_t  (>= 0 always)
}

__global__ __launch_bounds__(256) void max_kernel(const float* __restrict__ values,
                                                  unsigned int* __restrict__ vmax_bits) {
    __shared__ float smax[4];
    float m = 0.f;  // values >= 0
    for (int i = blockIdx.x * blockDim.x + threadIdx.x; i < N_SAMPLES;
         i += gridDim.x * blockDim.x)
        m = fmaxf(m, values[i]);
#pragma unroll
    for (int off = 32; off > 0; off >>= 1)
        m = fmaxf(m, __shfl_xor(m, off, 64));
    if ((threadIdx.x & 63) == 0) smax[threadIdx.x >> 6] = m;
    __syncthreads();
    if (threadIdx.x == 0) {
        float bm = fmaxf(fmaxf(smax[0], smax[1]), fmaxf(smax[2], smax[3]));
        atomicMax(vmax_bits, __float_as_uint(bm));  // valid: non-negative floats
    }
}

__global__ __launch_bounds__(256) void hist_kernel(const float* __restrict__ values,
                                                   const unsigned int* __restrict__ vmax_bits,
                                                   unsigned int* __restrict__ counts,
                                                   float* __restrict__ sums) {
    __shared__ unsigned int lc[BINS];
    __shared__ float ls[BINS];
    if (threadIdx.x < BINS) { lc[threadIdx.x] = 0u; ls[threadIdx.x] = 0.f; }
    __syncthreads();

    const float vmax = __uint_as_float(*vmax_bits);
    float edges[BINS + 1];
#pragma unroll
    for (int j = 0; j <= BINS; ++j) edges[j] = (float)j / 10.0f;  // match jnp.arange/10
    edges[BINS] += 1e-6f;

    for (int i = blockIdx.x * blockDim.x + threadIdx.x; i < N_SAMPLES;
         i += gridDim.x * blockDim.x) {
        float v = values[i];
        float vc = v / vmax;
        // searchsorted(edges, vc, side='right') - 1  ==  (#edges <= vc) - 1
        int bin = -1;
#pragma unroll
        for (int j = 0; j <= BINS; ++j) bin += (edges[j] <= vc) ? 1 : 0;
        bin = min(max(bin, 0), BINS - 1);
        atomicAdd(&lc[bin], 1u);
        atomicAdd(&ls[bin], v);
    }
    __syncthreads();
    if (threadIdx.x < BINS) {
        if (lc[threadIdx.x]) {
            atomicAdd(&counts[threadIdx.x], lc[threadIdx.x]);
            atomicAdd(&sums[threadIdx.x], ls[threadIdx.x]);
        }
    }
}

__global__ void final_kernel(const unsigned int* __restrict__ counts,
                             const float* __restrict__ sums,
                             float* __restrict__ out) {
    if (threadIdx.x == 0 && blockIdx.x == 0) {
        int nn = 0;
        float acc = 0.f;
#pragma unroll
        for (int b = 0; b < BINS; ++b) {
            unsigned int c = counts[b];
            if (c > 0u) { ++nn; acc += sums[b] / (float)c; }
        }
        float nne = (nn > 0) ? (float)nn : 1.f;
        out[0] = acc / nne;   // == sum_i weights[i] * values[i]
    }
}

extern "C" void kernel_launch(void* const* d_in, const int* in_sizes, int n_in,
                              void* d_out, int out_size, void* d_ws, size_t ws_size,
                              hipStream_t stream) {
    const float* pred = (const float*)d_in[0];
    const int* target = (const int*)d_in[1];
    float* out = (float*)d_out;

    float* values = (float*)d_ws;
    unsigned int* stats = (unsigned int*)((char*)d_ws + (size_t)N_SAMPLES * sizeof(float));
    unsigned int* counts = stats + 1;
    float* sums = (float*)(stats + 11);

    // zero vmax + counts + sums (ws is poisoned 0xAA before every call)
    hipMemsetAsync(stats, 0, 21 * sizeof(unsigned int), stream);

    values_kernel<<<N_SAMPLES / 4, 256, 0, stream>>>(pred, target, values);
    max_kernel<<<256, 256, 0, stream>>>(values, stats);
    hist_kernel<<<256, 256, 0, stream>>>(values, stats, counts, sums);
    final_kernel<<<1, 64, 0, stream>>>(counts, sums, out);
}